// Round 1
// baseline (1774.761 us; speedup 1.0000x reference)
//
#include <hip/hip_runtime.h>
#include <hip/hip_bf16.h>
#include <math.h>

#define WAVE 64

// ---------------- CSR construction ----------------

__global__ void k_hist(const int* __restrict__ dst, int* __restrict__ deg, int nE) {
    for (int e = blockIdx.x * blockDim.x + threadIdx.x; e < nE; e += gridDim.x * blockDim.x) {
        atomicAdd(&deg[dst[e]], 1);
    }
}

// single-block scan over N (<= 1024*chunk) elements: rowstart (exclusive), cursor copy, dinv = rsqrt(deg+1)
__global__ void k_scan(const int* __restrict__ deg, int* __restrict__ rowstart,
                       int* __restrict__ cursor, float* __restrict__ dinv, int n, int nE) {
    __shared__ int sums[1024];
    int t = threadIdx.x;
    int chunk = (n + 1023) >> 10;
    int lo = t * chunk;
    int hi = min(n, lo + chunk);
    int s = 0;
    for (int i = lo; i < hi; ++i) s += deg[i];
    sums[t] = s;
    __syncthreads();
    // Hillis-Steele inclusive scan over 1024 block sums
    for (int d = 1; d < 1024; d <<= 1) {
        int v = (t >= d) ? sums[t - d] : 0;
        __syncthreads();
        sums[t] += v;
        __syncthreads();
    }
    int run = sums[t] - s;  // exclusive prefix for this chunk
    for (int i = lo; i < hi; ++i) {
        int d = deg[i];
        rowstart[i] = run;
        cursor[i] = run;
        dinv[i] = rsqrtf((float)(d + 1));
        run += d;
    }
    if (t == 0) rowstart[n] = nE;
}

__global__ void k_fill(const int* __restrict__ src, const int* __restrict__ dst,
                       int* __restrict__ cursor, int* __restrict__ csr, int nE) {
    for (int e = blockIdx.x * blockDim.x + threadIdx.x; e < nE; e += gridDim.x * blockDim.x) {
        int d = dst[e];
        int pos = atomicAdd(&cursor[d], 1);
        csr[pos] = src[e];
    }
}

// ---------------- GCN conv (wave per node) ----------------
// h1 = tanh( (sum_e dinv[s]*x[s] * dinv[i] + dinv[i]^2 * x[i]) @ W + b )

__global__ void k_gcn(const float* __restrict__ x, const int* __restrict__ csr,
                      const int* __restrict__ rowstart, const float* __restrict__ dinv,
                      const float* __restrict__ W, const float* __restrict__ b,
                      float* __restrict__ h1, int n) {
    int wid = (blockIdx.x * blockDim.x + threadIdx.x) >> 6;
    if (wid >= n) return;
    int lane = threadIdx.x & 63;
    int g = lane >> 4;       // edge slot 0..3
    int f = lane & 15;       // feature 0..15
    int r0 = rowstart[wid];
    int r1 = rowstart[wid + 1];
    float acc = 0.f;
    for (int e = r0 + g; e < r1; e += 4) {
        int s = csr[e];
        acc += dinv[s] * x[s * 16 + f];
    }
    acc += __shfl_xor(acc, 16);
    acc += __shfl_xor(acc, 32);
    float di = dinv[wid];
    float a = di * acc + di * di * x[wid * 16 + f];
    // a: aggregated feature f, replicated across the 4 groups
    float y = b[f];
#pragma unroll
    for (int k = 0; k < 16; ++k) {
        float ak = __shfl(a, (lane & 48) | k);
        y += ak * W[k * 16 + f];
    }
    if (g == 0) h1[wid * 16 + f] = tanhf(y);
}

// ---------------- SAGE conv (wave per node) ----------------
// out = normalize( mean_agg @ Wl + bl + x @ Wr ), optional tanh

template <int TANH>
__global__ void k_sage(const float* __restrict__ hin, const int* __restrict__ csr,
                       const int* __restrict__ rowstart,
                       const float* __restrict__ Wl, const float* __restrict__ bl,
                       const float* __restrict__ Wr,
                       float* __restrict__ hout, int n) {
    int wid = (blockIdx.x * blockDim.x + threadIdx.x) >> 6;
    if (wid >= n) return;
    int lane = threadIdx.x & 63;
    int g = lane >> 4;
    int f = lane & 15;
    int r0 = rowstart[wid];
    int r1 = rowstart[wid + 1];
    float acc = 0.f;
    for (int e = r0 + g; e < r1; e += 4) {
        int s = csr[e];
        acc += hin[s * 16 + f];
    }
    acc += __shfl_xor(acc, 16);
    acc += __shfl_xor(acc, 32);
    float agg = acc / fmaxf((float)(r1 - r0), 1.0f);
    float hf = hin[wid * 16 + f];
    float y = bl[f];
#pragma unroll
    for (int k = 0; k < 16; ++k) {
        float ak = __shfl(agg, (lane & 48) | k);
        float hk = __shfl(hf, (lane & 48) | k);
        y += ak * Wl[k * 16 + f] + hk * Wr[k * 16 + f];
    }
    // L2 normalize over the 16 features (within each 16-lane group)
    float sq = y * y;
    sq += __shfl_xor(sq, 1);
    sq += __shfl_xor(sq, 2);
    sq += __shfl_xor(sq, 4);
    sq += __shfl_xor(sq, 8);
    float nrm = sqrtf(sq);
    y = y / fmaxf(nrm, 1e-12f);
    if (TANH) y = tanhf(y);
    if (g == 0) hout[wid * 16 + f] = y;
}

// ---------------- Fused MLP: 16 -> 128 -> 128 -> 1 (thread per node) ----------------
// t1 kept in VGPRs (all compile-time indices); W matrices read with wave-uniform
// addresses -> scalar loads; no LDS.

__global__ void k_mlp(const float* __restrict__ h3,
                      const float* __restrict__ W1, const float* __restrict__ b1,
                      const float* __restrict__ W2, const float* __restrict__ b2,
                      const float* __restrict__ W3, const float* __restrict__ b3,
                      float* __restrict__ out, int n) {
    int node = blockIdx.x * blockDim.x + threadIdx.x;
    if (node >= n) return;
    float h[16];
    const float4* hp = (const float4*)(h3 + node * 16);
    float4 v0 = hp[0], v1 = hp[1], v2 = hp[2], v3 = hp[3];
    h[0] = v0.x; h[1] = v0.y; h[2] = v0.z; h[3] = v0.w;
    h[4] = v1.x; h[5] = v1.y; h[6] = v1.z; h[7] = v1.w;
    h[8] = v2.x; h[9] = v2.y; h[10] = v2.z; h[11] = v2.w;
    h[12] = v3.x; h[13] = v3.y; h[14] = v3.z; h[15] = v3.w;

    float t1[128];
#pragma unroll
    for (int j = 0; j < 128; ++j) {
        float acc = b1[j];
#pragma unroll
        for (int k = 0; k < 16; ++k) acc += h[k] * W1[k * 128 + j];
        t1[j] = fmaxf(acc, 0.f);
    }

    float out3 = b3[0];
    for (int jc = 0; jc < 8; ++jc) {  // runtime loop: W2 index stays uniform, acc/t1 compile-time
        float acc[16];
#pragma unroll
        for (int j = 0; j < 16; ++j) acc[j] = b2[jc * 16 + j];
#pragma unroll
        for (int k = 0; k < 128; ++k) {
            float tk = t1[k];
#pragma unroll
            for (int j = 0; j < 16; ++j) acc[j] += tk * W2[k * 128 + jc * 16 + j];
        }
#pragma unroll
        for (int j = 0; j < 16; ++j) out3 += fmaxf(acc[j], 0.f) * W3[jc * 16 + j];
    }
    out[node] = out3;
}

// ---------------- launch ----------------

extern "C" void kernel_launch(void* const* d_in, const int* in_sizes, int n_in,
                              void* d_out, int out_size, void* d_ws, size_t ws_size,
                              hipStream_t stream) {
    const float* x = (const float*)d_in[0];
    const int* ei = (const int*)d_in[1];
    const float* W_gcn = (const float*)d_in[2];
    const float* b_gcn = (const float*)d_in[3];
    const float* Wl1 = (const float*)d_in[4];
    const float* bl1 = (const float*)d_in[5];
    const float* Wr1 = (const float*)d_in[6];
    const float* Wl2 = (const float*)d_in[7];
    const float* bl2 = (const float*)d_in[8];
    const float* Wr2 = (const float*)d_in[9];
    const float* W1 = (const float*)d_in[10];
    const float* b1 = (const float*)d_in[11];
    const float* W2 = (const float*)d_in[12];
    const float* b2 = (const float*)d_in[13];
    const float* W3 = (const float*)d_in[14];
    const float* b3 = (const float*)d_in[15];

    const int N = in_sizes[0] / 16;
    const int E = in_sizes[1] / 2;
    const int* src = ei;
    const int* dst = ei + E;

    // workspace carve-up (256B aligned)
    char* w = (char*)d_ws;
    auto alloc = [&](size_t bytes) {
        void* p = (void*)w;
        w += (bytes + 255) & ~(size_t)255;
        return p;
    };
    int* deg = (int*)alloc((size_t)N * 4);
    int* rowstart = (int*)alloc((size_t)(N + 1) * 4);
    int* cursor = (int*)alloc((size_t)N * 4);
    float* dinv = (float*)alloc((size_t)N * 4);
    int* csr = (int*)alloc((size_t)E * 4);
    float* h1 = (float*)alloc((size_t)N * 16 * 4);
    float* h2 = (float*)alloc((size_t)N * 16 * 4);
    float* h3 = (float*)alloc((size_t)N * 16 * 4);

    hipMemsetAsync(deg, 0, (size_t)N * 4, stream);

    int blk = 256;
    int egrid = min(2048, (E + blk - 1) / blk);
    k_hist<<<egrid, blk, 0, stream>>>(dst, deg, E);
    k_scan<<<1, 1024, 0, stream>>>(deg, rowstart, cursor, dinv, N, E);
    k_fill<<<egrid, blk, 0, stream>>>(src, dst, cursor, csr, E);

    long long waves_threads = (long long)N * WAVE;
    int ggrid = (int)((waves_threads + blk - 1) / blk);
    k_gcn<<<ggrid, blk, 0, stream>>>(x, csr, rowstart, dinv, W_gcn, b_gcn, h1, N);
    k_sage<1><<<ggrid, blk, 0, stream>>>(h1, csr, rowstart, Wl1, bl1, Wr1, h2, N);
    k_sage<0><<<ggrid, blk, 0, stream>>>(h2, csr, rowstart, Wl2, bl2, Wr2, h3, N);

    int mgrid = (N + blk - 1) / blk;
    k_mlp<<<mgrid, blk, 0, stream>>>(h3, W1, b1, W2, b2, W3, b3, (float*)d_out, N);
}